// Round 1
// baseline (684.353 us; speedup 1.0000x reference)
//
#include <hip/hip_runtime.h>
#include <cfloat>
#include <cstddef>

// Problem constants
#define NROWS 65536          // 64 * 32 * 32 flattened rows
#define KCB   1024           // codebook entries
#define DDIM  64             // embedding dim
#define QSIZE 4194304        // 64*64*32*32
#define POFF  (1 + QSIZE)    // perplexity position in d_out
#define EOFF  (2 + QSIZE)    // encodings start in d_out

// ws layout:
//   [0, 262144)        idx   int32[65536]
//   [262144, 266240)   counts int32[1024]
//   [266240, 266244)   loss accumulator float
//   [266244, 270340)   esq  float[1024]

// ---------------------------------------------------------------------------
// Kernel 0: ||e_k||^2, computed as fp64 sum of fp32-rounded squares
// ---------------------------------------------------------------------------
__global__ void k_esq(const float* __restrict__ E, float* __restrict__ esq) {
    int k = blockIdx.x * 256 + threadIdx.x;
    if (k < KCB) {
        double s = 0.0;
        #pragma unroll
        for (int d = 0; d < DDIM; ++d) {
            float v = E[(k << 6) + d];
            float sq = v * v;           // fp32-rounded square (matches np x**2)
            s += (double)sq;
        }
        esq[k] = (float)s;
    }
}

// ---------------------------------------------------------------------------
// Kernel 1: distances + argmin. Block = 64 rows x all K.
// Threads: rt = tid>>5 (8 row-groups of 8 rows), kt = tid&31 (4 k's each, K-tile 128)
// dot accumulated in fp32 chunks of 8 d's, combined in fp64 -> near-exact.
// dist = (||x||^2 - 2*dot) + ||e||^2 with reference fp32 rounding order.
// ---------------------------------------------------------------------------
__launch_bounds__(256)
__global__ void k_argmin(const float* __restrict__ x, const float* __restrict__ E,
                         const float* __restrict__ esq, int* __restrict__ out_idx) {
    __shared__ float xs[DDIM * 68];    // xs[c*68 + r], r in [0,64)
    __shared__ float ks[DDIM * 132];   // ks[c*132 + kk], kk in [0,128)
    __shared__ float As[64];

    const int tid = threadIdx.x;
    const int bb  = blockIdx.x;
    const int n0  = bb * 64;
    const int b   = n0 >> 10;          // image index
    const int p0  = n0 & 1023;         // pixel offset within image

    // Stage x tile (NCHW gather, coalesced along pixels)
    for (int i = tid; i < 64 * 64; i += 256) {
        int c = i >> 6, r = i & 63;
        xs[c * 68 + r] = x[(((size_t)(b * 64 + c)) << 10) + p0 + r];
    }
    __syncthreads();

    // ||x_n||^2 per row (fp64 sum of fp32 squares)
    if (tid < 64) {
        double s = 0.0;
        #pragma unroll
        for (int c = 0; c < 64; ++c) {
            float v = xs[c * 68 + tid];
            float sq = v * v;
            s += (double)sq;
        }
        As[tid] = (float)s;
    }
    __syncthreads();

    const int rt = tid >> 5;
    const int kt = tid & 31;

    float Ar[8];
    #pragma unroll
    for (int r = 0; r < 8; ++r) Ar[r] = As[rt * 8 + r];

    float best[8]; int bidx[8];
    #pragma unroll
    for (int r = 0; r < 8; ++r) { best[r] = FLT_MAX; bidx[r] = 0; }

    for (int t = 0; t < 8; ++t) {
        __syncthreads();   // protect ks reuse across tiles
        // stage codebook tile transposed: ks[c][kk] = E[t*128+kk][c]
        for (int i = tid; i < 128 * 64; i += 256) {
            int kk = i >> 6, c = i & 63;
            ks[c * 132 + kk] = E[((size_t)(t * 128 + kk) << 6) + c];
        }
        __syncthreads();

        float eq[4];
        #pragma unroll
        for (int j = 0; j < 4; ++j) eq[j] = esq[t * 128 + kt * 4 + j];

        double acc64[8][4];
        #pragma unroll
        for (int r = 0; r < 8; ++r)
            #pragma unroll
            for (int j = 0; j < 4; ++j) acc64[r][j] = 0.0;

        #pragma unroll
        for (int ch = 0; ch < 8; ++ch) {
            float a32[8][4];
            #pragma unroll
            for (int r = 0; r < 8; ++r)
                #pragma unroll
                for (int j = 0; j < 4; ++j) a32[r][j] = 0.0f;
            #pragma unroll
            for (int dd = 0; dd < 8; ++dd) {
                int d = ch * 8 + dd;
                const float4 xa = *(const float4*)&xs[d * 68 + rt * 8];
                const float4 xb = *(const float4*)&xs[d * 68 + rt * 8 + 4];
                const float4 kv = *(const float4*)&ks[d * 132 + kt * 4];
                float xr[8] = {xa.x, xa.y, xa.z, xa.w, xb.x, xb.y, xb.z, xb.w};
                float kk4[4] = {kv.x, kv.y, kv.z, kv.w};
                #pragma unroll
                for (int r = 0; r < 8; ++r)
                    #pragma unroll
                    for (int j = 0; j < 4; ++j)
                        a32[r][j] = fmaf(xr[r], kk4[j], a32[r][j]);
            }
            #pragma unroll
            for (int r = 0; r < 8; ++r)
                #pragma unroll
                for (int j = 0; j < 4; ++j) acc64[r][j] += (double)a32[r][j];
        }

        #pragma unroll
        for (int r = 0; r < 8; ++r) {
            #pragma unroll
            for (int j = 0; j < 4; ++j) {
                float dotf = (float)acc64[r][j];
                float dist = (Ar[r] - 2.0f * dotf) + eq[j];   // reference rounding order
                int kg = t * 128 + kt * 4 + j;
                if (dist < best[r] || (dist == best[r] && kg < bidx[r])) {
                    best[r] = dist; bidx[r] = kg;
                }
            }
        }
    }

    // reduce (min, first-index) across the 32 kt lanes sharing each row group
    #pragma unroll
    for (int r = 0; r < 8; ++r) {
        float v = best[r]; int ii = bidx[r];
        #pragma unroll
        for (int off = 16; off > 0; off >>= 1) {
            float ov = __shfl_xor(v, off, 32);
            int   oi = __shfl_xor(ii, off, 32);
            if (ov < v || (ov == v && oi < ii)) { v = ov; ii = oi; }
        }
        if (kt == 0) out_idx[n0 + rt * 8 + r] = ii;
    }
}

// ---------------------------------------------------------------------------
// Kernel 2: quantized output (NCHW) + sum of squared diffs for loss
// ---------------------------------------------------------------------------
__global__ void k_quant(const float* __restrict__ x, const float* __restrict__ E,
                        const int* __restrict__ idx, float* __restrict__ out_q,
                        float* __restrict__ loss_acc) {
    int gid = blockIdx.x * 256 + threadIdx.x;     // 0 .. 4194303 (NCHW flat)
    int p = gid & 1023;
    int c = (gid >> 10) & 63;
    int b = gid >> 16;
    int n = (b << 10) | p;
    int id = idx[n];
    float q  = E[(id << 6) + c];
    float xv = x[gid];
    out_q[gid] = q;                               // quantized_st forward == quantized
    float df = q - xv;
    float val = df * df;
    #pragma unroll
    for (int off = 32; off > 0; off >>= 1) val += __shfl_down(val, off, 64);
    __shared__ float wsum[4];
    int lane = threadIdx.x & 63, w = threadIdx.x >> 6;
    if (lane == 0) wsum[w] = val;
    __syncthreads();
    if (threadIdx.x == 0)
        atomicAdd(loss_acc, wsum[0] + wsum[1] + wsum[2] + wsum[3]);
}

// ---------------------------------------------------------------------------
// Kernel 3: histogram of indices (LDS privatized)
// ---------------------------------------------------------------------------
__global__ void k_hist(const int* __restrict__ idx, int* __restrict__ counts) {
    __shared__ int h[KCB];
    for (int i = threadIdx.x; i < KCB; i += 256) h[i] = 0;
    __syncthreads();
    for (int n = blockIdx.x * 256 + threadIdx.x; n < NROWS; n += gridDim.x * 256)
        atomicAdd(&h[idx[n]], 1);
    __syncthreads();
    for (int i = threadIdx.x; i < KCB; i += 256)
        if (h[i]) atomicAdd(&counts[i], h[i]);
}

// ---------------------------------------------------------------------------
// Kernel 4: finalize loss + perplexity
// ---------------------------------------------------------------------------
__global__ void k_final(const int* __restrict__ counts, const float* __restrict__ loss_acc,
                        float* __restrict__ out) {
    int i = threadIdx.x;                          // 1024 threads
    float p = (float)counts[i] / 65536.0f;
    float v = p * logf(p + 1e-10f);
    #pragma unroll
    for (int off = 32; off > 0; off >>= 1) v += __shfl_down(v, off, 64);
    __shared__ float sb[16];
    int lane = threadIdx.x & 63, w = threadIdx.x >> 6;
    if (lane == 0) sb[w] = v;
    __syncthreads();
    if (threadIdx.x == 0) {
        float s = 0.0f;
        #pragma unroll
        for (int k = 0; k < 16; ++k) s += sb[k];
        out[POFF] = expf(-s);
        out[0] = 1.25f * (*loss_acc) / 4194304.0f;
    }
}

// ---------------------------------------------------------------------------
// Kernel 5: one-hot encodings, one block per row, full-row write (no memset pass)
// Offset EOFF is 8B-aligned but not 16B-aligned -> float2 stores.
// ---------------------------------------------------------------------------
__global__ void k_enc(const int* __restrict__ idx, float* __restrict__ enc) {
    int n = blockIdx.x;
    int id = idx[n];
    int t = threadIdx.x;
    size_t base = (size_t)n * KCB;
    int p0 = t * 2, p1 = t * 2 + 512;
    float2 a, bb;
    a.x  = (id == p0)     ? 1.0f : 0.0f;
    a.y  = (id == p0 + 1) ? 1.0f : 0.0f;
    bb.x = (id == p1)     ? 1.0f : 0.0f;
    bb.y = (id == p1 + 1) ? 1.0f : 0.0f;
    *(float2*)(enc + base + p0) = a;
    *(float2*)(enc + base + p1) = bb;
}

extern "C" void kernel_launch(void* const* d_in, const int* in_sizes, int n_in,
                              void* d_out, int out_size, void* d_ws, size_t ws_size,
                              hipStream_t stream) {
    const float* x = (const float*)d_in[0];   // [64,64,32,32] NCHW fp32
    const float* E = (const float*)d_in[1];   // [1024,64] fp32
    float* out = (float*)d_out;
    char* ws = (char*)d_ws;
    int*   idxp     = (int*)ws;
    int*   counts   = (int*)(ws + 262144);
    float* loss_acc = (float*)(ws + 266240);
    float* esq      = (float*)(ws + 266244);

    // zero counts + loss accumulator (ws is poisoned each call)
    hipMemsetAsync(ws + 262144, 0, 4100, stream);

    k_esq   <<<4,     256, 0, stream>>>(E, esq);
    k_argmin<<<1024,  256, 0, stream>>>(x, E, esq, idxp);
    k_quant <<<16384, 256, 0, stream>>>(x, E, idxp, out + 1, loss_acc);
    k_hist  <<<64,    256, 0, stream>>>(idxp, counts);
    k_final <<<1,    1024, 0, stream>>>(counts, loss_acc, out);
    k_enc   <<<65536, 256, 0, stream>>>(idxp, out + (size_t)EOFF);
}

// Round 2
// 488.328 us; speedup vs baseline: 1.4014x; 1.4014x over previous
//
#include <hip/hip_runtime.h>
#include <cfloat>
#include <cstddef>

// Problem constants
#define NROWS 65536          // 64 * 32 * 32 flattened rows
#define KCB   1024           // codebook entries
#define DDIM  64             // embedding dim
#define QSIZE 4194304        // 64*64*32*32
#define POFF  (1 + QSIZE)    // perplexity position in d_out
#define EOFF  (2 + QSIZE)    // encodings start in d_out
#define NQBLK 16384          // k_quant grid size

// ws layout:
//   [0, 262144)          idx      int32[65536]
//   [262144, 266240)     counts   int32[1024]
//   [266240, 270336)     esq      float[1024]
//   [270336, 335872)     partials float[16384]  (per-block loss sums, no memset needed)

// ---------------------------------------------------------------------------
// Kernel 0: ||e_k||^2, computed as fp64 sum of fp32-rounded squares
// ---------------------------------------------------------------------------
__global__ void k_esq(const float* __restrict__ E, float* __restrict__ esq) {
    int k = blockIdx.x * 256 + threadIdx.x;
    if (k < KCB) {
        double s = 0.0;
        #pragma unroll
        for (int d = 0; d < DDIM; ++d) {
            float v = E[(k << 6) + d];
            float sq = v * v;           // fp32-rounded square (matches np x**2)
            s += (double)sq;
        }
        esq[k] = (float)s;
    }
}

// ---------------------------------------------------------------------------
// Kernel 1: distances + argmin. Block = 64 rows x all K.
// Threads: rt = tid>>5 (8 row-groups of 8 rows), kt = tid&31 (4 k's each, K-tile 128)
// dot accumulated in fp32 chunks of 8 d's, combined in fp64 -> near-exact.
// dist = (||x||^2 - 2*dot) + ||e||^2 with reference fp32 rounding order.
// ---------------------------------------------------------------------------
__launch_bounds__(256)
__global__ void k_argmin(const float* __restrict__ x, const float* __restrict__ E,
                         const float* __restrict__ esq, int* __restrict__ out_idx) {
    __shared__ float xs[DDIM * 68];    // xs[c*68 + r], r in [0,64)
    __shared__ float ks[DDIM * 132];   // ks[c*132 + kk], kk in [0,128)
    __shared__ float As[64];

    const int tid = threadIdx.x;
    const int bb  = blockIdx.x;
    const int n0  = bb * 64;
    const int b   = n0 >> 10;          // image index
    const int p0  = n0 & 1023;         // pixel offset within image

    // Stage x tile (NCHW gather, coalesced along pixels)
    for (int i = tid; i < 64 * 64; i += 256) {
        int c = i >> 6, r = i & 63;
        xs[c * 68 + r] = x[(((size_t)(b * 64 + c)) << 10) + p0 + r];
    }
    __syncthreads();

    // ||x_n||^2 per row (fp64 sum of fp32 squares)
    if (tid < 64) {
        double s = 0.0;
        #pragma unroll
        for (int c = 0; c < 64; ++c) {
            float v = xs[c * 68 + tid];
            float sq = v * v;
            s += (double)sq;
        }
        As[tid] = (float)s;
    }
    __syncthreads();

    const int rt = tid >> 5;
    const int kt = tid & 31;

    float Ar[8];
    #pragma unroll
    for (int r = 0; r < 8; ++r) Ar[r] = As[rt * 8 + r];

    float best[8]; int bidx[8];
    #pragma unroll
    for (int r = 0; r < 8; ++r) { best[r] = FLT_MAX; bidx[r] = 0; }

    for (int t = 0; t < 8; ++t) {
        __syncthreads();   // protect ks reuse across tiles
        // stage codebook tile transposed: ks[c][kk] = E[t*128+kk][c]
        for (int i = tid; i < 128 * 64; i += 256) {
            int kk = i >> 6, c = i & 63;
            ks[c * 132 + kk] = E[((size_t)(t * 128 + kk) << 6) + c];
        }
        __syncthreads();

        float eq[4];
        #pragma unroll
        for (int j = 0; j < 4; ++j) eq[j] = esq[t * 128 + kt * 4 + j];

        double acc64[8][4];
        #pragma unroll
        for (int r = 0; r < 8; ++r)
            #pragma unroll
            for (int j = 0; j < 4; ++j) acc64[r][j] = 0.0;

        #pragma unroll
        for (int ch = 0; ch < 8; ++ch) {
            float a32[8][4];
            #pragma unroll
            for (int r = 0; r < 8; ++r)
                #pragma unroll
                for (int j = 0; j < 4; ++j) a32[r][j] = 0.0f;
            #pragma unroll
            for (int dd = 0; dd < 8; ++dd) {
                int d = ch * 8 + dd;
                const float4 xa = *(const float4*)&xs[d * 68 + rt * 8];
                const float4 xb = *(const float4*)&xs[d * 68 + rt * 8 + 4];
                const float4 kv = *(const float4*)&ks[d * 132 + kt * 4];
                float xr[8] = {xa.x, xa.y, xa.z, xa.w, xb.x, xb.y, xb.z, xb.w};
                float kk4[4] = {kv.x, kv.y, kv.z, kv.w};
                #pragma unroll
                for (int r = 0; r < 8; ++r)
                    #pragma unroll
                    for (int j = 0; j < 4; ++j)
                        a32[r][j] = fmaf(xr[r], kk4[j], a32[r][j]);
            }
            #pragma unroll
            for (int r = 0; r < 8; ++r)
                #pragma unroll
                for (int j = 0; j < 4; ++j) acc64[r][j] += (double)a32[r][j];
        }

        #pragma unroll
        for (int r = 0; r < 8; ++r) {
            #pragma unroll
            for (int j = 0; j < 4; ++j) {
                float dotf = (float)acc64[r][j];
                float dist = (Ar[r] - 2.0f * dotf) + eq[j];   // reference rounding order
                int kg = t * 128 + kt * 4 + j;
                if (dist < best[r] || (dist == best[r] && kg < bidx[r])) {
                    best[r] = dist; bidx[r] = kg;
                }
            }
        }
    }

    // reduce (min, first-index) across the 32 kt lanes sharing each row group
    #pragma unroll
    for (int r = 0; r < 8; ++r) {
        float v = best[r]; int ii = bidx[r];
        #pragma unroll
        for (int off = 16; off > 0; off >>= 1) {
            float ov = __shfl_xor(v, off, 32);
            int   oi = __shfl_xor(ii, off, 32);
            if (ov < v || (ov == v && oi < ii)) { v = ov; ii = oi; }
        }
        if (kt == 0) out_idx[n0 + rt * 8 + r] = ii;
    }
}

// ---------------------------------------------------------------------------
// Kernel 2: quantized output (NCHW) + per-block partial loss sum (NO atomics —
// single-address fp32 atomicAdd from 16K blocks serialized cross-XCD: 213 us)
// ---------------------------------------------------------------------------
__global__ void k_quant(const float* __restrict__ x, const float* __restrict__ E,
                        const int* __restrict__ idx, float* __restrict__ out_q,
                        float* __restrict__ partials) {
    int gid = blockIdx.x * 256 + threadIdx.x;     // 0 .. 4194303 (NCHW flat)
    int p = gid & 1023;
    int c = (gid >> 10) & 63;
    int b = gid >> 16;
    int n = (b << 10) | p;
    int id = idx[n];
    float q  = E[(id << 6) + c];
    float xv = x[gid];
    out_q[gid] = q;                               // quantized_st forward == quantized
    float df = q - xv;
    float val = df * df;
    #pragma unroll
    for (int off = 32; off > 0; off >>= 1) val += __shfl_down(val, off, 64);
    __shared__ float wsum[4];
    int lane = threadIdx.x & 63, w = threadIdx.x >> 6;
    if (lane == 0) wsum[w] = val;
    __syncthreads();
    if (threadIdx.x == 0)
        partials[blockIdx.x] = wsum[0] + wsum[1] + wsum[2] + wsum[3];
}

// ---------------------------------------------------------------------------
// Kernel 3: histogram of indices (LDS privatized)
// ---------------------------------------------------------------------------
__global__ void k_hist(const int* __restrict__ idx, int* __restrict__ counts) {
    __shared__ int h[KCB];
    for (int i = threadIdx.x; i < KCB; i += 256) h[i] = 0;
    __syncthreads();
    for (int n = blockIdx.x * 256 + threadIdx.x; n < NROWS; n += gridDim.x * 256)
        atomicAdd(&h[idx[n]], 1);
    __syncthreads();
    for (int i = threadIdx.x; i < KCB; i += 256)
        if (h[i]) atomicAdd(&counts[i], h[i]);
}

// ---------------------------------------------------------------------------
// Kernel 4: finalize loss (reduce 16384 partials in fp64) + perplexity
// ---------------------------------------------------------------------------
__global__ void k_final(const int* __restrict__ counts, const float* __restrict__ partials,
                        float* __restrict__ out) {
    int tid = threadIdx.x;                        // 1024 threads
    double ls = 0.0;
    for (int i = tid; i < NQBLK; i += 1024) ls += (double)partials[i];
    float p = (float)counts[tid] / 65536.0f;
    float v = p * logf(p + 1e-10f);
    #pragma unroll
    for (int off = 32; off > 0; off >>= 1) {
        v  += __shfl_down(v, off, 64);
        ls += __shfl_down(ls, off, 64);
    }
    __shared__ float  sb[16];
    __shared__ double lb[16];
    int lane = tid & 63, w = tid >> 6;
    if (lane == 0) { sb[w] = v; lb[w] = ls; }
    __syncthreads();
    if (tid == 0) {
        float s = 0.0f; double L = 0.0;
        #pragma unroll
        for (int k = 0; k < 16; ++k) { s += sb[k]; L += lb[k]; }
        out[POFF] = expf(-s);
        out[0] = (float)(1.25 * L / 4194304.0);
    }
}

// ---------------------------------------------------------------------------
// Kernel 5: one-hot encodings, one block per row, full-row write (no memset pass)
// Offset EOFF is 8B-aligned but not 16B-aligned -> float2 stores.
// ---------------------------------------------------------------------------
__global__ void k_enc(const int* __restrict__ idx, float* __restrict__ enc) {
    int n = blockIdx.x;
    int id = idx[n];
    int t = threadIdx.x;
    size_t base = (size_t)n * KCB;
    int p0 = t * 2, p1 = t * 2 + 512;
    float2 a, bb;
    a.x  = (id == p0)     ? 1.0f : 0.0f;
    a.y  = (id == p0 + 1) ? 1.0f : 0.0f;
    bb.x = (id == p1)     ? 1.0f : 0.0f;
    bb.y = (id == p1 + 1) ? 1.0f : 0.0f;
    *(float2*)(enc + base + p0) = a;
    *(float2*)(enc + base + p1) = bb;
}

extern "C" void kernel_launch(void* const* d_in, const int* in_sizes, int n_in,
                              void* d_out, int out_size, void* d_ws, size_t ws_size,
                              hipStream_t stream) {
    const float* x = (const float*)d_in[0];   // [64,64,32,32] NCHW fp32
    const float* E = (const float*)d_in[1];   // [1024,64] fp32
    float* out = (float*)d_out;
    char* ws = (char*)d_ws;
    int*   idxp     = (int*)ws;
    int*   counts   = (int*)(ws + 262144);
    float* esq      = (float*)(ws + 266240);
    float* partials = (float*)(ws + 270336);

    // zero counts (ws is poisoned each call); partials fully overwritten, no memset
    hipMemsetAsync(ws + 262144, 0, 4096, stream);

    k_esq   <<<4,     256, 0, stream>>>(E, esq);
    k_argmin<<<1024,  256, 0, stream>>>(x, E, esq, idxp);
    k_quant <<<NQBLK, 256, 0, stream>>>(x, E, idxp, out + 1, partials);
    k_hist  <<<64,    256, 0, stream>>>(idxp, counts);
    k_final <<<1,    1024, 0, stream>>>(counts, partials, out);
    k_enc   <<<65536, 256, 0, stream>>>(idxp, out + (size_t)EOFF);
}

// Round 3
// 419.321 us; speedup vs baseline: 1.6321x; 1.1646x over previous
//
#include <hip/hip_runtime.h>
#include <cfloat>
#include <cstddef>

// Problem constants
#define NROWS 65536          // 64 * 32 * 32 flattened rows
#define KCB   1024           // codebook entries
#define DDIM  64             // embedding dim
#define QSIZE 4194304        // 64*64*32*32
#define POFF  (1 + QSIZE)    // perplexity position in d_out
#define EOFF  (2 + QSIZE)    // encodings start in d_out
#define NQBLK 16384          // k_quant grid size
#define TAU   2.0e-3f        // phase-A certainty margin (worst-case err bound ~1.6e-4)

// ws layout:
//   [0, 262144)          idx      int32[65536]
//   [262144, 266240)     counts   int32[1024]
//   [266240, 270336)     esq      float[1024]
//   [270336, 335872)     partials float[16384]
//   [335872, 466944)     Eh       bf16[65536]   (hi split of codebook)
//   [466944, 598016)     El       bf16[65536]   (lo split)
//   [598016, 602112)     flagcnt  int32[1024]   (per phase-A block)
//   [602112, 864256)     flagrows int32[1024*64]

typedef __attribute__((ext_vector_type(8))) short bf16x8;
typedef __attribute__((ext_vector_type(4))) float floatx4;

__device__ __forceinline__ unsigned short f2bf(float f) {
    unsigned u = __float_as_uint(f);
    u += 0x7FFF + ((u >> 16) & 1);          // round-to-nearest-even
    return (unsigned short)(u >> 16);
}
__device__ __forceinline__ float bf2f(unsigned short h) {
    return __uint_as_float(((unsigned)h) << 16);
}

// ---------------------------------------------------------------------------
// Kernel 0: ||e_k||^2 (fp64 sum of fp32 squares) + bf16 hi/lo split of E
// ---------------------------------------------------------------------------
__global__ void k_esq(const float* __restrict__ E, float* __restrict__ esq,
                      unsigned short* __restrict__ Eh, unsigned short* __restrict__ El) {
    int k = blockIdx.x * 256 + threadIdx.x;
    if (k < KCB) {
        double s = 0.0;
        #pragma unroll
        for (int d = 0; d < DDIM; ++d) {
            float v = E[(k << 6) + d];
            float sq = v * v;
            s += (double)sq;
            unsigned short h = f2bf(v);
            unsigned short l = f2bf(v - bf2f(h));
            Eh[(k << 6) + d] = h;
            El[(k << 6) + d] = l;
        }
        esq[k] = (float)s;
    }
}

// ---------------------------------------------------------------------------
// Phase A: approximate distances via bf16-split MFMA (hh + hl + lh passes),
// per-row top-2 tracking of (esq_k - 2*dot)  [ ||x||^2 is row-constant ].
// Rows with top-2 gap <= TAU are flagged for exact re-check.
// Verified layouts (m89/m120): A[m=lane&15][k=quad*8+j], B[n=lane&15][k=quad*8+j],
// D: row=quad*4+reg, col=lane&15.
// ---------------------------------------------------------------------------
__launch_bounds__(256)
__global__ void k_amin_mfma(const float* __restrict__ x,
                            const unsigned short* __restrict__ Eh,
                            const unsigned short* __restrict__ El,
                            const float* __restrict__ esq,
                            int* __restrict__ out_idx,
                            int* __restrict__ flagcnt,
                            int* __restrict__ flagrows) {
    // E chunk in LDS: 128 k-rows, stride 72 bf16 (144 B = 9*16 -> aligned, 2-way banks)
    __shared__ unsigned short ehs[128 * 72];
    __shared__ unsigned short els[128 * 72];
    __shared__ float eqs[128];
    __shared__ int fl_cnt;
    __shared__ int fl_list[64];

    const int tid  = threadIdx.x;
    const int bb   = blockIdx.x;
    const int n0   = bb * 64;
    const int b    = n0 >> 10;
    const int p0   = n0 & 1023;
    const int wid  = tid >> 6;
    const int lane = tid & 63;
    const int li   = lane & 15;
    const int quad = lane >> 4;

    if (tid == 0) fl_cnt = 0;

    // A-frags direct from global (coalesced in 16-lane runs), bf16 hi/lo split
    bf16x8 axh0, axl0, axh1, axl1;
    const int colbase = p0 + wid * 16 + li;
    #pragma unroll
    for (int j = 0; j < 8; ++j) {
        float v0 = x[(size_t)(b * 64 + quad * 8 + j) * 1024 + colbase];
        float v1 = x[(size_t)(b * 64 + 32 + quad * 8 + j) * 1024 + colbase];
        unsigned short h0 = f2bf(v0);
        unsigned short l0 = f2bf(v0 - bf2f(h0));
        unsigned short h1 = f2bf(v1);
        unsigned short l1 = f2bf(v1 - bf2f(h1));
        axh0[j] = (short)h0; axl0[j] = (short)l0;
        axh1[j] = (short)h1; axl1[j] = (short)l1;
    }

    float b1[4], b2[4]; int i1[4];
    #pragma unroll
    for (int r = 0; r < 4; ++r) { b1[r] = FLT_MAX; b2[r] = FLT_MAX; i1[r] = 0; }

    for (int c = 0; c < 8; ++c) {
        __syncthreads();
        // stage chunk of Eh/El (bf16, pre-split) + esq
        for (int u = tid; u < 1024; u += 256) {
            int kl = u >> 3, d8 = u & 7;
            const size_t src = ((size_t)(c * 128 + kl) << 6) + d8 * 8;
            *(uint4*)&ehs[kl * 72 + d8 * 8] = *(const uint4*)&Eh[src];
            *(uint4*)&els[kl * 72 + d8 * 8] = *(const uint4*)&El[src];
        }
        for (int u = tid; u < 128; u += 256) eqs[u] = esq[c * 128 + u];
        __syncthreads();

        #pragma unroll
        for (int kt = 0; kt < 8; ++kt) {
            const int krow = (kt * 16 + li) * 72 + quad * 8;
            const bf16x8 bh0 = *(const bf16x8*)&ehs[krow];
            const bf16x8 bh1 = *(const bf16x8*)&ehs[krow + 32];
            const bf16x8 bl0 = *(const bf16x8*)&els[krow];
            const bf16x8 bl1 = *(const bf16x8*)&els[krow + 32];
            floatx4 cc = {0.f, 0.f, 0.f, 0.f};
            cc = __builtin_amdgcn_mfma_f32_16x16x32_bf16(axh0, bh0, cc, 0, 0, 0);
            cc = __builtin_amdgcn_mfma_f32_16x16x32_bf16(axh1, bh1, cc, 0, 0, 0);
            cc = __builtin_amdgcn_mfma_f32_16x16x32_bf16(axh0, bl0, cc, 0, 0, 0);
            cc = __builtin_amdgcn_mfma_f32_16x16x32_bf16(axh1, bl1, cc, 0, 0, 0);
            cc = __builtin_amdgcn_mfma_f32_16x16x32_bf16(axl0, bh0, cc, 0, 0, 0);
            cc = __builtin_amdgcn_mfma_f32_16x16x32_bf16(axl1, bh1, cc, 0, 0, 0);
            const float eq = eqs[kt * 16 + li];
            const int kglob = c * 128 + kt * 16 + li;
            #pragma unroll
            for (int r = 0; r < 4; ++r) {
                float dv = fmaf(-2.0f, cc[r], eq);
                bool lt = dv < b1[r];
                b2[r] = lt ? b1[r] : fminf(b2[r], dv);
                i1[r] = lt ? kglob : i1[r];
                b1[r] = lt ? dv : b1[r];
            }
        }
    }

    // merge top-2 across the 16 lanes of each quad-group
    #pragma unroll
    for (int r = 0; r < 4; ++r) {
        float v1v = b1[r]; int vi = i1[r]; float v2v = b2[r];
        #pragma unroll
        for (int off = 8; off > 0; off >>= 1) {
            float o1 = __shfl_xor(v1v, off, 16);
            int   oi = __shfl_xor(vi,  off, 16);
            float o2 = __shfl_xor(v2v, off, 16);
            float nb2 = fminf(fminf(v2v, o2), fmaxf(v1v, o1));
            bool take = (o1 < v1v) || (o1 == v1v && oi < vi);
            v1v = take ? o1 : v1v;
            vi  = take ? oi : vi;
            v2v = nb2;
        }
        b1[r] = v1v; i1[r] = vi; b2[r] = v2v;
    }

    if (li == 0) {
        const int m0 = n0 + wid * 16;
        #pragma unroll
        for (int r = 0; r < 4; ++r) {
            int row = m0 + quad * 4 + r;
            out_idx[row] = i1[r];
            if (b2[r] - b1[r] <= TAU) {
                int pos = atomicAdd(&fl_cnt, 1);
                fl_list[pos] = row;
            }
        }
    }
    __syncthreads();
    if (tid == 0) flagcnt[bb] = fl_cnt;
    for (int u = tid; u < fl_cnt; u += 256) flagrows[bb * 64 + u] = fl_list[u];
}

// ---------------------------------------------------------------------------
// Phase B: exact re-check of flagged rows with the R1 fp64-chunk method
// (empirically matches numpy over 65536 rows). Overwrites out_idx.
// ---------------------------------------------------------------------------
__launch_bounds__(256)
__global__ void k_amin_exact(const float* __restrict__ x, const float* __restrict__ E,
                             const float* __restrict__ esq,
                             const int* __restrict__ flagcnt, const int* __restrict__ flagrows,
                             int* __restrict__ out_idx) {
    const int bb = blockIdx.x;
    const int cnt = flagcnt[bb];
    if (cnt == 0) return;
    __shared__ float xr[64];
    __shared__ float rbest[4]; __shared__ int ribest[4];
    const int tid = threadIdx.x;
    for (int fi = 0; fi < cnt; ++fi) {
        const int row = flagrows[bb * 64 + fi];
        const int b = row >> 10, p = row & 1023;
        __syncthreads();
        if (tid < 64) xr[tid] = x[(size_t)(b * 64 + tid) * 1024 + p];
        __syncthreads();
        double As = 0.0;
        #pragma unroll
        for (int d = 0; d < 64; ++d) { float v = xr[d]; float sq = v * v; As += (double)sq; }
        float A = (float)As;
        float bd = FLT_MAX; int bi = 0;
        #pragma unroll
        for (int kk = 0; kk < 4; ++kk) {
            int k = tid * 4 + kk;
            const float* Ek = E + ((size_t)k << 6);
            double acc = 0.0;
            #pragma unroll
            for (int ch = 0; ch < 8; ++ch) {
                float a32 = 0.f;
                #pragma unroll
                for (int dd = 0; dd < 8; ++dd) {
                    int d = ch * 8 + dd;
                    a32 = fmaf(xr[d], Ek[d], a32);
                }
                acc += (double)a32;
            }
            float dist = (A - 2.0f * (float)acc) + esq[k];
            if (dist < bd) { bd = dist; bi = k; }      // ascending k -> lowest-idx ties
        }
        #pragma unroll
        for (int off = 32; off > 0; off >>= 1) {
            float od = __shfl_down(bd, off, 64);
            int   oi = __shfl_down(bi, off, 64);
            if (od < bd || (od == bd && oi < bi)) { bd = od; bi = oi; }
        }
        if ((tid & 63) == 0) { rbest[tid >> 6] = bd; ribest[tid >> 6] = bi; }
        __syncthreads();
        if (tid == 0) {
            float fb = rbest[0]; int fk = ribest[0];
            for (int wq = 1; wq < 4; ++wq)
                if (rbest[wq] < fb || (rbest[wq] == fb && ribest[wq] < fk)) { fb = rbest[wq]; fk = ribest[wq]; }
            out_idx[row] = fk;
        }
    }
}

// ---------------------------------------------------------------------------
// Kernel 2: quantized output (NCHW) + per-block partial loss sum (no atomics)
// ---------------------------------------------------------------------------
__global__ void k_quant(const float* __restrict__ x, const float* __restrict__ E,
                        const int* __restrict__ idx, float* __restrict__ out_q,
                        float* __restrict__ partials) {
    int gid = blockIdx.x * 256 + threadIdx.x;
    int p = gid & 1023;
    int c = (gid >> 10) & 63;
    int b = gid >> 16;
    int n = (b << 10) | p;
    int id = idx[n];
    float q  = E[(id << 6) + c];
    float xv = x[gid];
    out_q[gid] = q;
    float df = q - xv;
    float val = df * df;
    #pragma unroll
    for (int off = 32; off > 0; off >>= 1) val += __shfl_down(val, off, 64);
    __shared__ float wsum[4];
    int lane = threadIdx.x & 63, w = threadIdx.x >> 6;
    if (lane == 0) wsum[w] = val;
    __syncthreads();
    if (threadIdx.x == 0)
        partials[blockIdx.x] = wsum[0] + wsum[1] + wsum[2] + wsum[3];
}

// ---------------------------------------------------------------------------
// Kernel 3: histogram of indices (LDS privatized)
// ---------------------------------------------------------------------------
__global__ void k_hist(const int* __restrict__ idx, int* __restrict__ counts) {
    __shared__ int h[KCB];
    for (int i = threadIdx.x; i < KCB; i += 256) h[i] = 0;
    __syncthreads();
    for (int n = blockIdx.x * 256 + threadIdx.x; n < NROWS; n += gridDim.x * 256)
        atomicAdd(&h[idx[n]], 1);
    __syncthreads();
    for (int i = threadIdx.x; i < KCB; i += 256)
        if (h[i]) atomicAdd(&counts[i], h[i]);
}

// ---------------------------------------------------------------------------
// Kernel 4: finalize loss (fp64 partial reduce) + perplexity
// ---------------------------------------------------------------------------
__global__ void k_final(const int* __restrict__ counts, const float* __restrict__ partials,
                        float* __restrict__ out) {
    int tid = threadIdx.x;                        // 1024 threads
    double ls = 0.0;
    for (int i = tid; i < NQBLK; i += 1024) ls += (double)partials[i];
    float p = (float)counts[tid] / 65536.0f;
    float v = p * logf(p + 1e-10f);
    #pragma unroll
    for (int off = 32; off > 0; off >>= 1) {
        v  += __shfl_down(v, off, 64);
        ls += __shfl_down(ls, off, 64);
    }
    __shared__ float  sb[16];
    __shared__ double lb[16];
    int lane = tid & 63, w = tid >> 6;
    if (lane == 0) { sb[w] = v; lb[w] = ls; }
    __syncthreads();
    if (tid == 0) {
        float s = 0.0f; double L = 0.0;
        #pragma unroll
        for (int k = 0; k < 16; ++k) { s += sb[k]; L += lb[k]; }
        out[POFF] = expf(-s);
        out[0] = (float)(1.25 * L / 4194304.0);
    }
}

// ---------------------------------------------------------------------------
// Kernel 5: one-hot encodings, full-row write (EOFF is 8B-aligned -> float2)
// ---------------------------------------------------------------------------
__global__ void k_enc(const int* __restrict__ idx, float* __restrict__ enc) {
    int n = blockIdx.x;
    int id = idx[n];
    int t = threadIdx.x;
    size_t base = (size_t)n * KCB;
    int p0 = t * 2, p1 = t * 2 + 512;
    float2 a, bb;
    a.x  = (id == p0)     ? 1.0f : 0.0f;
    a.y  = (id == p0 + 1) ? 1.0f : 0.0f;
    bb.x = (id == p1)     ? 1.0f : 0.0f;
    bb.y = (id == p1 + 1) ? 1.0f : 0.0f;
    *(float2*)(enc + base + p0) = a;
    *(float2*)(enc + base + p1) = bb;
}

extern "C" void kernel_launch(void* const* d_in, const int* in_sizes, int n_in,
                              void* d_out, int out_size, void* d_ws, size_t ws_size,
                              hipStream_t stream) {
    const float* x = (const float*)d_in[0];   // [64,64,32,32] NCHW fp32
    const float* E = (const float*)d_in[1];   // [1024,64] fp32
    float* out = (float*)d_out;
    char* ws = (char*)d_ws;
    int*   idxp     = (int*)ws;
    int*   counts   = (int*)(ws + 262144);
    float* esq      = (float*)(ws + 266240);
    float* partials = (float*)(ws + 270336);
    unsigned short* Ehw = (unsigned short*)(ws + 335872);
    unsigned short* Elw = (unsigned short*)(ws + 466944);
    int* flagcnt    = (int*)(ws + 598016);
    int* flagrows   = (int*)(ws + 602112);

    hipMemsetAsync(ws + 262144, 0, 4096, stream);   // counts only

    k_esq       <<<4,     256, 0, stream>>>(E, esq, Ehw, Elw);
    k_amin_mfma <<<1024,  256, 0, stream>>>(x, Ehw, Elw, esq, idxp, flagcnt, flagrows);
    k_amin_exact<<<1024,  256, 0, stream>>>(x, E, esq, flagcnt, flagrows, idxp);
    k_quant     <<<NQBLK, 256, 0, stream>>>(x, E, idxp, out + 1, partials);
    k_hist      <<<64,    256, 0, stream>>>(idxp, counts);
    k_final     <<<1,    1024, 0, stream>>>(counts, partials, out);
    k_enc       <<<65536, 256, 0, stream>>>(idxp, out + (size_t)EOFF);
}